// Round 9
// baseline (323.374 us; speedup 1.0000x reference)
//
#include <hip/hip_runtime.h>
#include <hip/hip_bf16.h>

#define NF 128

typedef float f4 __attribute__((ext_vector_type(4)));
typedef short s16x8 __attribute__((ext_vector_type(8)));
typedef unsigned short u16x8 __attribute__((ext_vector_type(8)));

static __device__ __forceinline__ unsigned short f2b(float f) {
    union { float f; unsigned u; } c; c.f = f;
    unsigned r = c.u + 0x7fffu + ((c.u >> 16) & 1u);
    return (unsigned short)(r >> 16);
}
static __device__ __forceinline__ float blo(unsigned v) { return __uint_as_float(v << 16); }
static __device__ __forceinline__ float bhi(unsigned v) { return __uint_as_float(v & 0xffff0000u); }

// ---------------- zero scratch ----------------
__global__ __launch_bounds__(256) void k_zero(int* __restrict__ p, int nwords) {
    int i = blockIdx.x * 256 + threadIdx.x;
    if (i < nwords) p[i] = 0;
}

// ---------------- x -> bf16 row-major [N][128] (u32 = 2 feats) ----------------
__global__ __launch_bounds__(256) void k_cvt(const float* __restrict__ x,
                                             unsigned* __restrict__ out32, int N) {
    int i = blockIdx.x * 256 + threadIdx.x;
    if (i >= N * 64) return;
    int n = i >> 6, l = i & 63;
    float2 v = *(const float2*)(x + (size_t)n * NF + l * 2);
    out32[(size_t)n * 64 + l] = (unsigned)f2b(v.x) | ((unsigned)f2b(v.y) << 16);
}

// ---------------- degree count, XCD-localized ----------------
__global__ __launch_bounds__(256) void k_deg(const int* __restrict__ ei, int E,
                                             int* __restrict__ deg, int nper) {
    int b = blockIdx.x;
    int i = (b >> 3) * 256 + threadIdx.x;
    if (i >= E) return;
    int d = ei[E + i];
    int lo = (b & 7) * nper;
    if (d >= lo && d < lo + nper) atomicAdd(&deg[d], 1);
}

// ---------------- 3-kernel deterministic exclusive scan over deg ----------------
__global__ __launch_bounds__(256) void k_scanA(const int* __restrict__ deg, int N,
                                               int* __restrict__ bsum) {
    __shared__ int red[256];
    int tid = threadIdx.x;
    int i = blockIdx.x * 256 + tid;
    int v = (i < N) ? deg[i] : 0;
    red[tid] = v; __syncthreads();
    for (int s = 128; s > 0; s >>= 1) {
        if (tid < s) red[tid] += red[tid + s];
        __syncthreads();
    }
    if (tid == 0) bsum[blockIdx.x] = red[0];
}

__global__ __launch_bounds__(256) void k_scanB(const int* __restrict__ bsum, int NB,
                                               int* __restrict__ bbase) {
    __shared__ int sc[256];
    int tid = threadIdx.x;
    int v = (tid < NB) ? bsum[tid] : 0;
    sc[tid] = v; __syncthreads();
    for (int s = 1; s < 256; s <<= 1) {
        int t = (tid >= s) ? sc[tid - s] : 0;
        __syncthreads();
        sc[tid] += t;
        __syncthreads();
    }
    bbase[tid] = sc[tid] - v;   // exclusive
}

__global__ __launch_bounds__(256) void k_scanC(const int* __restrict__ deg, int N,
                                               const int* __restrict__ bbase,
                                               int* __restrict__ offs) {
    __shared__ int sc[256];
    int tid = threadIdx.x;
    int i = blockIdx.x * 256 + tid;
    int v = (i < N) ? deg[i] : 0;
    sc[tid] = v; __syncthreads();
    for (int s = 1; s < 256; s <<= 1) {
        int t = (tid >= s) ? sc[tid - s] : 0;
        __syncthreads();
        sc[tid] += t;
        __syncthreads();
    }
    if (i < N) {
        offs[i] = bbase[blockIdx.x] + sc[tid] - v;
        if (i == N - 1) offs[N] = bbase[blockIdx.x] + sc[tid];   // sentinel = E
    }
}

// ---------------- CSR fill (u16 src), XCD-localized like k_deg ----------------
__global__ __launch_bounds__(256) void k_fill(const int* __restrict__ ei, int E,
                                              const int* __restrict__ offs,
                                              int* __restrict__ cursor,
                                              unsigned short* __restrict__ csr,
                                              int nper) {
    int b = blockIdx.x;
    int i = (b >> 3) * 256 + threadIdx.x;
    if (i >= E) return;
    int d = ei[E + i];
    int lo = (b & 7) * nper;
    if (d >= lo && d < lo + nper) {
        int p = atomicAdd(&cursor[d], 1);
        csr[offs[d] + p] = (unsigned short)ei[i];
    }
}

// ---------------- weight prep -> bf16 MFMA B-layout, lane-contiguous ----------------
// Per layer (65536 u16): ks*4096 + (col>>4)*512 + (kq*16 + (col&15))*8 + kk:
// MFMA lane l reads bytes l*16 of each (ks,c) 1KB sub-block -> conflict-free LDS.
// mats: 0=W1l(L0 half0), 1=W1r(L0 half1), 2=W2l(L1 half0).
__global__ __launch_bounds__(256) void k_prep_w(const float* __restrict__ w0,
                                                const float* __restrict__ w1,
                                                const float* __restrict__ w2,
                                                unsigned short* __restrict__ wt) {
    int t = blockIdx.x * 256 + threadIdx.x;     // 0..6143
    if (t >= 6144) return;
    int mat = t >> 11, rem = t & 2047;
    int col = rem >> 4, ks = (rem >> 2) & 3, qq = rem & 3;
    const float* W = (mat == 0) ? w0 : (mat == 1) ? w1 : w2;
    int layer = (mat == 2) ? 1 : 0, half = (mat == 1) ? 1 : 0;
    const float* src = W + col * NF + ks * 32 + qq * 8;
    u16x8 d;
#pragma unroll
    for (int j = 0; j < 8; ++j) d[j] = f2b(src[j]);
    *(u16x8*)(wt + layer * 65536 + (half * 4 + ks) * 4096 + (col >> 4) * 512 +
              (qq * 16 + (col & 15)) * 8) = d;
}

// ---------------- layer-2 lin_r weight: fold BN scale/shift exactly ----------------
__global__ __launch_bounds__(256) void k_prep_w2(const float* __restrict__ w2r,
                                                 const float* __restrict__ sbn,
                                                 const float* __restrict__ b2l,
                                                 const float* __restrict__ bbn,
                                                 unsigned short* __restrict__ wtL2,
                                                 float* __restrict__ bias2) {
    if (blockIdx.x < 8) {
        int t = blockIdx.x * 256 + threadIdx.x;  // 0..2047
        int col = t >> 4, ks = (t >> 2) & 3, qq = t & 3;
        int k0 = ks * 32 + qq * 8;
        u16x8 d;
#pragma unroll
        for (int j = 0; j < 8; ++j) d[j] = f2b(w2r[col * NF + k0 + j] * sbn[k0 + j]);
        *(u16x8*)(wtL2 + (4 + ks) * 4096 + (col >> 4) * 512 +
                  (qq * 16 + (col & 15)) * 8) = d;
    } else {
        int f = threadIdx.x;
        if (f < NF) {
            float s = b2l[f];
            for (int k = 0; k < NF; ++k) s += w2r[f * NF + k] * bbn[k];
            bias2[f] = s;
        }
    }
}

// ---------------- fused layer: gather-mean -> MFMA lin -> epilogue ----------------
// 64 nodes/block. Phase A: 16-lane group gathers full 256B rows (uint4/lane,
// 8-deep unroll), mean (+BN fold for MODE2), writes bf16 row to LDS with XOR
// chunk-swizzle (chunk ^ (row&15)) so phase-B A-frag reads are conflict-free.
// Phase B: 4 waves x (16 rows x 128 cols), weights in LDS (lane-contiguous),
// bias + row-L2-norm; MODE1: relu + h1b store + BN stats; MODE2: fused FC head.
// C layout: col = lane&15, row = (lane>>4)*4 + reg [m89].
template <int MODE>
__global__ __launch_bounds__(256, 1) void k_layer(
    const uint4* __restrict__ T4,              // gather table [N][16] (bf16 rows)
    const unsigned short* __restrict__ srcA,   // [N][128] u16 view (lin_r A source)
    const unsigned short* __restrict__ csr,
    const int* __restrict__ offs,
    const unsigned short* __restrict__ wt,     // layer base, lane-contiguous
    const float* __restrict__ bias,            // [128] (layer2: BN-folded)
    const float* __restrict__ sbn, const float* __restrict__ bbn,   // MODE2
    const float* __restrict__ wfc, const float* __restrict__ bfc,   // MODE2
    unsigned short* __restrict__ outb,         // MODE1: h1b [N][128]
    float* __restrict__ outf,                  // MODE2: out [N][8]
    float* __restrict__ bnSum, float* __restrict__ bnSq, int N) {
    __shared__ __align__(16) unsigned short wlds[32768];   // 64 KB
    __shared__ __align__(16) unsigned short aggl[8192];    // 16 KB: 64 rows x 128
    __shared__ float sbuf[1024];                           // 4 KB

    int tid = threadIdx.x;
    int row0 = blockIdx.x * 64;

    // stage weights (issued first; latency overlaps gather phase)
    {
        const f4* ws4 = (const f4*)wt;
        f4* wd4 = (f4*)wlds;
#pragma unroll
        for (int it = 0; it < 16; ++it) wd4[tid + it * 256] = ws4[tid + it * 256];
    }
    if constexpr (MODE == 1) {
        if (tid < 256) sbuf[tid] = 0.f;
    } else {
        *(f4*)&sbuf[tid * 4] = ((const f4*)wfc)[tid];
    }

    // ---- phase A: gather-mean ----
    {
        int g = tid >> 4, li = tid & 15;
#pragma unroll 1
        for (int nn = 0; nn < 4; ++nn) {
            int nl = g * 4 + nn;
            int node = row0 + nl;
            int nc = node < N ? node : N - 1;       // clamp (outputs guarded)
            int beg = offs[nc], cnt = offs[nc + 1] - beg;
            const unsigned short* cp = csr + beg;
            float a0 = 0, a1 = 0, a2 = 0, a3 = 0, a4 = 0, a5 = 0, a6 = 0, a7 = 0;
            int j = 0;
            for (; j + 8 <= cnt; j += 8) {
                int s0 = cp[j + 0], s1 = cp[j + 1], s2 = cp[j + 2], s3 = cp[j + 3];
                int s4 = cp[j + 4], s5 = cp[j + 5], s6 = cp[j + 6], s7 = cp[j + 7];
                uint4 v0 = T4[(size_t)s0 * 16 + li];
                uint4 v1 = T4[(size_t)s1 * 16 + li];
                uint4 v2 = T4[(size_t)s2 * 16 + li];
                uint4 v3 = T4[(size_t)s3 * 16 + li];
                uint4 v4 = T4[(size_t)s4 * 16 + li];
                uint4 v5 = T4[(size_t)s5 * 16 + li];
                uint4 v6 = T4[(size_t)s6 * 16 + li];
                uint4 v7 = T4[(size_t)s7 * 16 + li];
                a0 += blo(v0.x) + blo(v1.x) + blo(v2.x) + blo(v3.x)
                    + blo(v4.x) + blo(v5.x) + blo(v6.x) + blo(v7.x);
                a1 += bhi(v0.x) + bhi(v1.x) + bhi(v2.x) + bhi(v3.x)
                    + bhi(v4.x) + bhi(v5.x) + bhi(v6.x) + bhi(v7.x);
                a2 += blo(v0.y) + blo(v1.y) + blo(v2.y) + blo(v3.y)
                    + blo(v4.y) + blo(v5.y) + blo(v6.y) + blo(v7.y);
                a3 += bhi(v0.y) + bhi(v1.y) + bhi(v2.y) + bhi(v3.y)
                    + bhi(v4.y) + bhi(v5.y) + bhi(v6.y) + bhi(v7.y);
                a4 += blo(v0.z) + blo(v1.z) + blo(v2.z) + blo(v3.z)
                    + blo(v4.z) + blo(v5.z) + blo(v6.z) + blo(v7.z);
                a5 += bhi(v0.z) + bhi(v1.z) + bhi(v2.z) + bhi(v3.z)
                    + bhi(v4.z) + bhi(v5.z) + bhi(v6.z) + bhi(v7.z);
                a6 += blo(v0.w) + blo(v1.w) + blo(v2.w) + blo(v3.w)
                    + blo(v4.w) + blo(v5.w) + blo(v6.w) + blo(v7.w);
                a7 += bhi(v0.w) + bhi(v1.w) + bhi(v2.w) + bhi(v3.w)
                    + bhi(v4.w) + bhi(v5.w) + bhi(v6.w) + bhi(v7.w);
            }
            for (; j < cnt; ++j) {
                uint4 v = T4[(size_t)cp[j] * 16 + li];
                a0 += blo(v.x); a1 += bhi(v.x); a2 += blo(v.y); a3 += bhi(v.y);
                a4 += blo(v.z); a5 += bhi(v.z); a6 += blo(v.w); a7 += bhi(v.w);
            }
            float id = (cnt > 0) ? 1.0f / (float)cnt : 0.f;
            a0 *= id; a1 *= id; a2 *= id; a3 *= id;
            a4 *= id; a5 *= id; a6 *= id; a7 *= id;
            if constexpr (MODE == 2) {
                if (cnt > 0) {   // mean(s*v+b) = s*mean(v)+b when deg>0, else 0
                    const float2* s2 = (const float2*)(sbn + li * 8);
                    const float2* b2 = (const float2*)(bbn + li * 8);
                    float2 sA = s2[0], sB = s2[1], sC = s2[2], sD = s2[3];
                    float2 bA = b2[0], bB = b2[1], bC = b2[2], bD = b2[3];
                    a0 = a0 * sA.x + bA.x; a1 = a1 * sA.y + bA.y;
                    a2 = a2 * sB.x + bB.x; a3 = a3 * sB.y + bB.y;
                    a4 = a4 * sC.x + bC.x; a5 = a5 * sC.y + bC.y;
                    a6 = a6 * sD.x + bD.x; a7 = a7 * sD.y + bD.y;
                }
            }
            uint4 p;
            p.x = (unsigned)f2b(a0) | ((unsigned)f2b(a1) << 16);
            p.y = (unsigned)f2b(a2) | ((unsigned)f2b(a3) << 16);
            p.z = (unsigned)f2b(a4) | ((unsigned)f2b(a5) << 16);
            p.w = (unsigned)f2b(a6) | ((unsigned)f2b(a7) << 16);
            int cs = li ^ (nl & 15);               // chunk swizzle
            *(uint4*)&aggl[nl * 128 + cs * 8] = p;
        }
    }
    __syncthreads();

    // ---- phase B: MFMA linear ----
    int lane = tid & 63;
    int q = lane >> 4, m = lane & 15;
    int row_base = row0 + (tid >> 6) * 16;
    int rml = (tid >> 6) * 16 + m;                 // local row in aggl

    s16x8 afr[8];
#pragma unroll
    for (int ks = 0; ks < 4; ++ks) {
        int cs = (ks * 4 + q) ^ (rml & 15);
        afr[ks] = *(const s16x8*)&aggl[rml * 128 + cs * 8];
    }
    int r = row_base + m; if (r >= N) r = N - 1;
#pragma unroll
    for (int ks = 0; ks < 4; ++ks)
        afr[4 + ks] = *(const s16x8*)(srcA + (size_t)r * NF + ks * 32 + q * 8);

    f4 acc[8];
#pragma unroll
    for (int c = 0; c < 8; ++c) acc[c] = (f4){0.f, 0.f, 0.f, 0.f};

    const unsigned short* wb = wlds + lane * 8;    // lane-contiguous
#pragma unroll
    for (int ks = 0; ks < 8; ++ks) {
#pragma unroll
        for (int c = 0; c < 8; ++c) {
            s16x8 bfr = *(const s16x8*)(wb + ks * 4096 + c * 512);
            acc[c] = __builtin_amdgcn_mfma_f32_16x16x32_bf16(afr[ks], bfr, acc[c], 0, 0, 0);
        }
    }

    // bias (col = c*16+m)
#pragma unroll
    for (int c = 0; c < 8; ++c) {
        float b = bias[c * 16 + m];
#pragma unroll
        for (int i = 0; i < 4; ++i) acc[c][i] += b;
    }
    // row L2 norm (row = row_base + q*4 + i, within 16 lanes of this q-group)
    float ss[4];
#pragma unroll
    for (int i = 0; i < 4; ++i) {
        float s = 0.f;
#pragma unroll
        for (int c = 0; c < 8; ++c) s += acc[c][i] * acc[c][i];
        s += __shfl_xor(s, 1); s += __shfl_xor(s, 2);
        s += __shfl_xor(s, 4); s += __shfl_xor(s, 8);
        ss[i] = 1.0f / fmaxf(sqrtf(s), 1e-12f);
    }
#pragma unroll
    for (int c = 0; c < 8; ++c)
#pragma unroll
        for (int i = 0; i < 4; ++i) acc[c][i] *= ss[i];

    if constexpr (MODE == 1) {
        // relu
#pragma unroll
        for (int c = 0; c < 8; ++c)
#pragma unroll
            for (int i = 0; i < 4; ++i) acc[c][i] = fmaxf(acc[c][i], 0.f);
        // store h1 bf16 row-major
#pragma unroll
        for (int i = 0; i < 4; ++i) {
            int row = row_base + q * 4 + i;
            if (row < N) {
#pragma unroll
                for (int c = 0; c < 8; ++c)
                    outb[(size_t)row * NF + c * 16 + m] = f2b(acc[c][i]);
            }
        }
        // BN partial sums per col over this wave's 16 rows
        float su[8], sq[8];
#pragma unroll
        for (int c = 0; c < 8; ++c) { su[c] = 0.f; sq[c] = 0.f; }
#pragma unroll
        for (int i = 0; i < 4; ++i) {
            bool vi = (row_base + q * 4 + i) < N;
#pragma unroll
            for (int c = 0; c < 8; ++c) {
                float u = vi ? acc[c][i] : 0.f;
                su[c] += u; sq[c] += u * u;
            }
        }
#pragma unroll
        for (int c = 0; c < 8; ++c) {
            su[c] += __shfl_xor(su[c], 16); su[c] += __shfl_xor(su[c], 32);
            sq[c] += __shfl_xor(sq[c], 16); sq[c] += __shfl_xor(sq[c], 32);
        }
        if (lane < 16) {
#pragma unroll
            for (int c = 0; c < 8; ++c) {
                atomicAdd(&sbuf[c * 16 + m], su[c]);
                atomicAdd(&sbuf[128 + c * 16 + m], sq[c]);
            }
        }
        __syncthreads();
        int shard = (blockIdx.x & 7) * 128;
        if (tid < 128)      atomicAdd(&bnSum[shard + tid], sbuf[tid]);
        else if (tid < 256) atomicAdd(&bnSq[shard + tid - 128], sbuf[tid]);
    } else {
        // fused FC head: out[row][cls] = sum_col h2[row][col]*wfc[cls][col] + bfc
        float o[8][4];
#pragma unroll
        for (int cls = 0; cls < 8; ++cls)
#pragma unroll
            for (int i = 0; i < 4; ++i) o[cls][i] = 0.f;
#pragma unroll
        for (int cls = 0; cls < 8; ++cls) {
#pragma unroll
            for (int c = 0; c < 8; ++c) {
                float wv = sbuf[cls * NF + c * 16 + m];
#pragma unroll
                for (int i = 0; i < 4; ++i) o[cls][i] += acc[c][i] * wv;
            }
#pragma unroll
            for (int i = 0; i < 4; ++i) {
                float t = o[cls][i];
                t += __shfl_xor(t, 1); t += __shfl_xor(t, 2);
                t += __shfl_xor(t, 4); t += __shfl_xor(t, 8);
                o[cls][i] = t;
            }
        }
        float sel[4] = {0.f, 0.f, 0.f, 0.f};
#pragma unroll
        for (int cls = 0; cls < 8; ++cls) {
            bool p = (m == cls);
#pragma unroll
            for (int i = 0; i < 4; ++i) sel[i] = p ? o[cls][i] : sel[i];
        }
        if (m < 8) {
            float bb = bfc[m];
#pragma unroll
            for (int i = 0; i < 4; ++i) {
                int row = row_base + q * 4 + i;
                if (row < N) outf[(size_t)row * 8 + m] = sel[i] + bb;
            }
        }
    }
}

// ---------------- BN finalize: sum shards, fold to scale/shift ----------------
__global__ void k_bnfin(const float* __restrict__ bnSum, const float* __restrict__ bnSq,
                        const float* __restrict__ gamma, const float* __restrict__ beta,
                        float* __restrict__ sbn, float* __restrict__ bbn, float n) {
    int f = threadIdx.x;
    float su = 0.f, sq = 0.f;
#pragma unroll
    for (int s = 0; s < 8; ++s) { su += bnSum[s * 128 + f]; sq += bnSq[s * 128 + f]; }
    float mu = su / n;
    float var = sq / n - mu * mu;
    var = fmaxf(var, 0.f);
    float s = gamma[f] / sqrtf(var + 1e-5f);
    sbn[f] = s;
    bbn[f] = beta[f] - mu * s;
}

extern "C" void kernel_launch(void* const* d_in, const int* in_sizes, int n_in,
                              void* d_out, int out_size, void* d_ws, size_t ws_size,
                              hipStream_t stream) {
    const float* x   = (const float*)d_in[0];
    const int*   ei  = (const int*)d_in[1];
    const float* W1l = (const float*)d_in[2];
    const float* b1l = (const float*)d_in[3];
    const float* W1r = (const float*)d_in[4];
    const float* gam = (const float*)d_in[5];
    const float* bet = (const float*)d_in[6];
    const float* W2l = (const float*)d_in[7];
    const float* b2l = (const float*)d_in[8];
    const float* W2r = (const float*)d_in[9];
    const float* Wfc = (const float*)d_in[10];
    const float* bfc = (const float*)d_in[11];
    int N = in_sizes[0] / NF;
    int E = in_sizes[1] / 2;

    char* w = (char*)d_ws;
    size_t o = 0;
#define ALO(nbytes) (o = (o + 255) & ~(size_t)255, o += (nbytes), (w + o - (nbytes)))
    int* deg    = (int*)ALO((size_t)N * 4);
    int* cursor = (int*)ALO((size_t)N * 4);
    float* bnSum = (float*)ALO(4096);          // 8 shards x 128
    float* bnSq  = (float*)ALO(4096);
    size_t zwords = o / 4;                     // zero region: deg, cursor, bn shards
    int* offs  = (int*)ALO((size_t)(N + 1) * 4);
    int* bsum  = (int*)ALO(1024);
    int* bbase = (int*)ALO(1024);
    unsigned short* csr = (unsigned short*)ALO((size_t)E * 2);
    unsigned short* wt  = (unsigned short*)ALO((size_t)2 * 65536 * 2);
    float* sbn   = (float*)ALO(512);
    float* bbn   = (float*)ALO(512);
    float* bias2 = (float*)ALO(512);
    unsigned short* xb  = (unsigned short*)ALO((size_t)N * NF * 2);  // [N][128] bf16
    unsigned short* h1b = (unsigned short*)ALO((size_t)N * NF * 2);  // [N][128] bf16
#undef ALO
    (void)ws_size; (void)n_in; (void)out_size;

    int NB = (N + 255) / 256;
    int EB8 = ((E + 255) / 256) * 8;
    int nper = (N + 7) / 8;
    int LB = (N + 63) / 64;
    int CV = (N * 64 + 255) / 256;

    k_zero<<<(int)((zwords + 255) / 256), 256, 0, stream>>>((int*)d_ws, (int)zwords);
    k_deg<<<EB8, 256, 0, stream>>>(ei, E, deg, nper);
    k_cvt<<<CV, 256, 0, stream>>>(x, (unsigned*)xb, N);
    k_prep_w<<<24, 256, 0, stream>>>(W1l, W1r, W2l, wt);
    k_scanA<<<NB, 256, 0, stream>>>(deg, N, bsum);
    k_scanB<<<1, 256, 0, stream>>>(bsum, NB, bbase);
    k_scanC<<<NB, 256, 0, stream>>>(deg, N, bbase, offs);
    k_fill<<<EB8, 256, 0, stream>>>(ei, E, offs, cursor, csr, nper);

    // layer 1 (fused gather + lin + relu/L2norm + BN stats)
    k_layer<1><<<LB, 256, 0, stream>>>((const uint4*)xb, xb, csr, offs, wt, b1l,
                                       nullptr, nullptr, nullptr, nullptr,
                                       h1b, nullptr, bnSum, bnSq, N);
    k_bnfin<<<1, 128, 0, stream>>>(bnSum, bnSq, gam, bet, sbn, bbn, (float)N);
    k_prep_w2<<<9, 256, 0, stream>>>(W2r, sbn, b2l, bbn, wt + 65536, bias2);
    // layer 2 (fused; BN folded into gather epilogue + lin_r weights) + FC head
    k_layer<2><<<LB, 256, 0, stream>>>((const uint4*)h1b, h1b, csr, offs, wt + 65536,
                                       bias2, sbn, bbn, Wfc, bfc,
                                       nullptr, (float*)d_out, nullptr, nullptr, N);
}

// Round 10
// 195.318 us; speedup vs baseline: 1.6556x; 1.6556x over previous
//
#include <hip/hip_runtime.h>
#include <hip/hip_bf16.h>

#define NF 128

typedef float f4 __attribute__((ext_vector_type(4)));
typedef short s16x8 __attribute__((ext_vector_type(8)));
typedef unsigned short u16x8 __attribute__((ext_vector_type(8)));

static __device__ __forceinline__ unsigned short f2b(float f) {
    union { float f; unsigned u; } c; c.f = f;
    unsigned r = c.u + 0x7fffu + ((c.u >> 16) & 1u);
    return (unsigned short)(r >> 16);
}
static __device__ __forceinline__ float blo(unsigned v) { return __uint_as_float(v << 16); }
static __device__ __forceinline__ float bhi(unsigned v) { return __uint_as_float(v & 0xffff0000u); }

// ---------------- fused prep: [0,ZB) zero ws | [ZB,ZB+CV) x->bf16 sliced | +24 w-prep ----
// x slice layout [4][N][32 feats]; weight layout lane-contiguous MFMA B (see below).
__global__ __launch_bounds__(256) void k_prep(int* __restrict__ zp, int nwords, int ZB,
                                              const float* __restrict__ x,
                                              unsigned* __restrict__ out32, int N,
                                              const float* __restrict__ w0,
                                              const float* __restrict__ w1,
                                              const float* __restrict__ w2,
                                              unsigned short* __restrict__ wt) {
    int b = blockIdx.x;
    if (b < ZB) {
        int i = b * 256 + threadIdx.x;
        if (i < nwords) zp[i] = 0;
    } else if (b < ZB + (N * 64 + 255) / 256) {
        int i = (b - ZB) * 256 + threadIdx.x;
        if (i >= N * 64) return;
        int n = i >> 6, l = i & 63;          // l = feature-pair 0..63
        int s = l >> 4, li = l & 15;         // slice, pair-within-slice
        float2 v = *(const float2*)(x + (size_t)n * NF + l * 2);
        out32[(size_t)s * N * 16 + (size_t)n * 16 + li] =
            (unsigned)f2b(v.x) | ((unsigned)f2b(v.y) << 16);
    } else {
        int t = (b - ZB - (N * 64 + 255) / 256) * 256 + threadIdx.x;   // 0..6143
        if (t >= 6144) return;
        int mat = t >> 11, rem = t & 2047;
        int col = rem >> 4, ks = (rem >> 2) & 3, qq = rem & 3;
        const float* W = (mat == 0) ? w0 : (mat == 1) ? w1 : w2;
        int layer = (mat == 2) ? 1 : 0, half = (mat == 1) ? 1 : 0;
        const float* src = W + col * NF + ks * 32 + qq * 8;
        u16x8 d;
#pragma unroll
        for (int j = 0; j < 8; ++j) d[j] = f2b(src[j]);
        *(u16x8*)(wt + layer * 65536 + (half * 4 + ks) * 4096 + (col >> 4) * 512 +
                  (qq * 16 + (col & 15)) * 8) = d;
    }
}

// ---------------- degree count, XCD-localized ----------------
__global__ __launch_bounds__(256) void k_deg(const int* __restrict__ ei, int E,
                                             int* __restrict__ deg, int nper) {
    int b = blockIdx.x;
    int i = (b >> 3) * 256 + threadIdx.x;
    if (i >= E) return;
    int d = ei[E + i];
    int lo = (b & 7) * nper;
    if (d >= lo && d < lo + nper) atomicAdd(&deg[d], 1);
}

// ---------------- 3-kernel deterministic exclusive scan over deg ----------------
__global__ __launch_bounds__(256) void k_scanA(const int* __restrict__ deg, int N,
                                               int* __restrict__ bsum) {
    __shared__ int red[256];
    int tid = threadIdx.x;
    int i = blockIdx.x * 256 + tid;
    int v = (i < N) ? deg[i] : 0;
    red[tid] = v; __syncthreads();
    for (int s = 128; s > 0; s >>= 1) {
        if (tid < s) red[tid] += red[tid + s];
        __syncthreads();
    }
    if (tid == 0) bsum[blockIdx.x] = red[0];
}

__global__ __launch_bounds__(256) void k_scanB(const int* __restrict__ bsum, int NB,
                                               int* __restrict__ bbase) {
    __shared__ int sc[256];
    int tid = threadIdx.x;
    int v = (tid < NB) ? bsum[tid] : 0;
    sc[tid] = v; __syncthreads();
    for (int s = 1; s < 256; s <<= 1) {
        int t = (tid >= s) ? sc[tid - s] : 0;
        __syncthreads();
        sc[tid] += t;
        __syncthreads();
    }
    bbase[tid] = sc[tid] - v;   // exclusive
}

__global__ __launch_bounds__(256) void k_scanC(const int* __restrict__ deg, int N,
                                               const int* __restrict__ bbase,
                                               int* __restrict__ offs) {
    __shared__ int sc[256];
    int tid = threadIdx.x;
    int i = blockIdx.x * 256 + tid;
    int v = (i < N) ? deg[i] : 0;
    sc[tid] = v; __syncthreads();
    for (int s = 1; s < 256; s <<= 1) {
        int t = (tid >= s) ? sc[tid - s] : 0;
        __syncthreads();
        sc[tid] += t;
        __syncthreads();
    }
    if (i < N) {
        offs[i] = bbase[blockIdx.x] + sc[tid] - v;
        if (i == N - 1) offs[N] = bbase[blockIdx.x] + sc[tid];   // sentinel = E
    }
}

// ---------------- CSR fill (u16 src), XCD-localized ----------------
__global__ __launch_bounds__(256) void k_fill(const int* __restrict__ ei, int E,
                                              const int* __restrict__ offs,
                                              int* __restrict__ cursor,
                                              unsigned short* __restrict__ csr,
                                              int nper) {
    int b = blockIdx.x;
    int i = (b >> 3) * 256 + threadIdx.x;
    if (i >= E) return;
    int d = ei[E + i];
    int lo = (b & 7) * nper;
    if (d >= lo && d < lo + nper) {
        int p = atomicAdd(&cursor[d], 1);
        csr[offs[d] + p] = (unsigned short)ei[i];
    }
}

// ---------------- BN finalize + layer-2 lin_r weight fold (merged) ----------------
// Every block re-derives sbn/bbn from the 8 BN shards (cheap); blocks 0-7 fold
// W2r*diag(s) into bf16 B-layout; block 8 computes bias2 and publishes sbn/bbn.
__global__ __launch_bounds__(256) void k_prep_w2(const float* __restrict__ bnSum,
                                                 const float* __restrict__ bnSq,
                                                 const float* __restrict__ gamma,
                                                 const float* __restrict__ beta,
                                                 const float* __restrict__ w2r,
                                                 const float* __restrict__ b2l,
                                                 unsigned short* __restrict__ wtL2,
                                                 float* __restrict__ bias2,
                                                 float* __restrict__ sbn,
                                                 float* __restrict__ bbn, float n) {
    __shared__ float sl[128], bl[128];
    int tid = threadIdx.x;
    if (tid < 128) {
        float su = 0.f, sq = 0.f;
#pragma unroll
        for (int s = 0; s < 8; ++s) { su += bnSum[s * 128 + tid]; sq += bnSq[s * 128 + tid]; }
        float mu = su / n;
        float var = fmaxf(sq / n - mu * mu, 0.f);
        float s = gamma[tid] / sqrtf(var + 1e-5f);
        sl[tid] = s;
        bl[tid] = beta[tid] - mu * s;
    }
    __syncthreads();
    if (blockIdx.x < 8) {
        int t = blockIdx.x * 256 + tid;          // 0..2047
        int col = t >> 4, ks = (t >> 2) & 3, qq = t & 3;
        int k0 = ks * 32 + qq * 8;
        u16x8 d;
#pragma unroll
        for (int j = 0; j < 8; ++j) d[j] = f2b(w2r[col * NF + k0 + j] * sl[k0 + j]);
        *(u16x8*)(wtL2 + (4 + ks) * 4096 + (col >> 4) * 512 +
                  (qq * 16 + (col & 15)) * 8) = d;
    } else {
        if (tid < NF) {
            float s = b2l[tid];
            for (int k = 0; k < NF; ++k) s += w2r[tid * NF + k] * bl[k];
            bias2[tid] = s;
            sbn[tid] = sl[tid];
            bbn[tid] = bl[tid];
        }
    }
}

// ---------------- aggregate, XCD-sliced, uint4 gathers, 4-deep ILP ----------------
// 16-lane group per node: nb=li>>2 (neighbor in quad), fq=li&3 (16B of the 64B row).
// 16-deep stage = 4 independent uint4 loads in flight (mean deg = 16).
template <bool TR>
__global__ __launch_bounds__(256) void k_agg(const uint4* __restrict__ T4all, // [4][N][4]
                                             const unsigned short* __restrict__ csr,
                                             const int* __restrict__ offs,
                                             const float* __restrict__ sbn,
                                             const float* __restrict__ bbn,
                                             uint4* __restrict__ outT4, int N) {
    int b = blockIdx.x;
    int s = (b & 7) >> 1;
    int chunk = (b >> 3) * 2 + (b & 1);
    int tid = threadIdx.x;
    int wid = tid >> 6, lane = tid & 63, g = lane >> 4, li = lane & 15;
    int node = chunk * 16 + wid * 4 + g;
    if (node >= N) return;
    int beg = offs[node], cnt = offs[node + 1] - beg;
    int nb = li >> 2, fq = li & 3;
    const uint4* T4 = T4all + (size_t)s * N * 4;
    const unsigned short* cp = csr + beg;
    float a0 = 0, a1 = 0, a2 = 0, a3 = 0, a4 = 0, a5 = 0, a6 = 0, a7 = 0;
    int j = 0;
    for (; j + 16 <= cnt; j += 16) {
        int sA = cp[j + nb], sB = cp[j + 4 + nb], sC = cp[j + 8 + nb], sD = cp[j + 12 + nb];
        uint4 vA = T4[(size_t)sA * 4 + fq];
        uint4 vB = T4[(size_t)sB * 4 + fq];
        uint4 vC = T4[(size_t)sC * 4 + fq];
        uint4 vD = T4[(size_t)sD * 4 + fq];
        a0 += (blo(vA.x) + blo(vB.x)) + (blo(vC.x) + blo(vD.x));
        a1 += (bhi(vA.x) + bhi(vB.x)) + (bhi(vC.x) + bhi(vD.x));
        a2 += (blo(vA.y) + blo(vB.y)) + (blo(vC.y) + blo(vD.y));
        a3 += (bhi(vA.y) + bhi(vB.y)) + (bhi(vC.y) + bhi(vD.y));
        a4 += (blo(vA.z) + blo(vB.z)) + (blo(vC.z) + blo(vD.z));
        a5 += (bhi(vA.z) + bhi(vB.z)) + (bhi(vC.z) + bhi(vD.z));
        a6 += (blo(vA.w) + blo(vB.w)) + (blo(vC.w) + blo(vD.w));
        a7 += (bhi(vA.w) + bhi(vB.w)) + (bhi(vC.w) + bhi(vD.w));
    }
    for (; j + 8 <= cnt; j += 8) {
        int sA = cp[j + nb], sB = cp[j + 4 + nb];
        uint4 vA = T4[(size_t)sA * 4 + fq];
        uint4 vB = T4[(size_t)sB * 4 + fq];
        a0 += blo(vA.x) + blo(vB.x); a1 += bhi(vA.x) + bhi(vB.x);
        a2 += blo(vA.y) + blo(vB.y); a3 += bhi(vA.y) + bhi(vB.y);
        a4 += blo(vA.z) + blo(vB.z); a5 += bhi(vA.z) + bhi(vB.z);
        a6 += blo(vA.w) + blo(vB.w); a7 += bhi(vA.w) + bhi(vB.w);
    }
    for (; j < cnt; j += 4) {
        int idx = j + nb;
        bool val = idx < cnt;
        int sA = cp[val ? idx : j];
        uint4 vA = T4[(size_t)sA * 4 + fq];
        if (val) {
            a0 += blo(vA.x); a1 += bhi(vA.x);
            a2 += blo(vA.y); a3 += bhi(vA.y);
            a4 += blo(vA.z); a5 += bhi(vA.z);
            a6 += blo(vA.w); a7 += bhi(vA.w);
        }
    }
    a0 += __shfl_xor(a0, 4); a1 += __shfl_xor(a1, 4);
    a2 += __shfl_xor(a2, 4); a3 += __shfl_xor(a3, 4);
    a4 += __shfl_xor(a4, 4); a5 += __shfl_xor(a5, 4);
    a6 += __shfl_xor(a6, 4); a7 += __shfl_xor(a7, 4);
    a0 += __shfl_xor(a0, 8); a1 += __shfl_xor(a1, 8);
    a2 += __shfl_xor(a2, 8); a3 += __shfl_xor(a3, 8);
    a4 += __shfl_xor(a4, 8); a5 += __shfl_xor(a5, 8);
    a6 += __shfl_xor(a6, 8); a7 += __shfl_xor(a7, 8);
    if (li < 4) {
        float id = (cnt > 0) ? 1.0f / (float)cnt : 0.f;
        float r[8] = {a0 * id, a1 * id, a2 * id, a3 * id,
                      a4 * id, a5 * id, a6 * id, a7 * id};
        if (TR) {
            if (cnt > 0) {   // mean(s*v+b) = s*mean(v)+b when deg>0, else 0
                const float2* sc2 = (const float2*)(sbn + s * 32 + fq * 8);
                const float2* bc2 = (const float2*)(bbn + s * 32 + fq * 8);
#pragma unroll
                for (int i = 0; i < 4; ++i) {
                    float2 sc = sc2[i], bc = bc2[i];
                    r[2 * i]     = r[2 * i]     * sc.x + bc.x;
                    r[2 * i + 1] = r[2 * i + 1] * sc.y + bc.y;
                }
            }
        }
        uint4 p;
        p.x = (unsigned)f2b(r[0]) | ((unsigned)f2b(r[1]) << 16);
        p.y = (unsigned)f2b(r[2]) | ((unsigned)f2b(r[3]) << 16);
        p.z = (unsigned)f2b(r[4]) | ((unsigned)f2b(r[5]) << 16);
        p.w = (unsigned)f2b(r[6]) | ((unsigned)f2b(r[7]) << 16);
        outT4[((size_t)s * N + node) * 4 + fq] = p;
    }
}

// ---------------- MFMA linear (+bias +L2norm), LDS-staged weights ----------------
// 64 rows/block, 4 waves; wave = 16 rows x 128 cols = 8 ks x 8 c mfma_16x16x32_bf16.
// Weights 64KB in LDS, lane-contiguous (each B-frag read = contiguous 1KB wave-span,
// 2 lanes/bank, conflict-free). C layout: col = lane&15, row = (lane>>4)*4 + reg.
template <int MODE>
__global__ __launch_bounds__(256, 2) void k_lin(
    const unsigned short* __restrict__ aggB,   // sliced [4][N][32] bf16
    const unsigned short* __restrict__ src2,   // sliced [4][N][32] bf16 (xb / h1b)
    const unsigned short* __restrict__ wt,     // layer base, lane-contiguous
    const float* __restrict__ bias,            // [128] (layer2: BN-folded)
    const float* __restrict__ wfc, const float* __restrict__ bfc,   // MODE2
    unsigned short* __restrict__ outb,         // MODE1: h1b sliced [4][N][32]
    float* __restrict__ outf,                  // MODE2: out [N,8]
    float* __restrict__ bnSum, float* __restrict__ bnSq, int N) {
    __shared__ __align__(16) unsigned short wlds[32768];   // 64 KB
    __shared__ float sbuf[1024];                           // 4 KB

    int tid = threadIdx.x;
    int lane = tid & 63;
    int q = lane >> 4, m = lane & 15;
    int row_base = blockIdx.x * 64 + (tid >> 6) * 16;

    // A-frag loads issued first (HBM latency hides under LDS staging)
    int r = row_base + m; if (r >= N) r = N - 1;           // clamp (outputs guarded)
    size_t rr = (size_t)r * 32 + q * 8;
    s16x8 afr[8];
#pragma unroll
    for (int ks = 0; ks < 4; ++ks) afr[ks] = *(const s16x8*)(aggB + (size_t)ks * N * 32 + rr);
#pragma unroll
    for (int ks = 0; ks < 4; ++ks) afr[4 + ks] = *(const s16x8*)(src2 + (size_t)ks * N * 32 + rr);

    // stage weights: 4096 f4 = 64 KB, 16 per thread
    {
        const f4* wsrc4 = (const f4*)wt;
        f4* wd4 = (f4*)wlds;
#pragma unroll
        for (int it = 0; it < 16; ++it) wd4[tid + it * 256] = wsrc4[tid + it * 256];
    }
    if constexpr (MODE == 1) {
        if (tid < 256) sbuf[tid] = 0.f;
    } else {
        *(f4*)&sbuf[tid * 4] = ((const f4*)wfc)[tid];      // 1024 floats
    }
    __syncthreads();

    f4 acc[8];
#pragma unroll
    for (int c = 0; c < 8; ++c) acc[c] = (f4){0.f, 0.f, 0.f, 0.f};

    const unsigned short* wb = wlds + lane * 8;            // lane-contiguous
#pragma unroll
    for (int ks = 0; ks < 8; ++ks) {
#pragma unroll
        for (int c = 0; c < 8; ++c) {
            s16x8 bfr = *(const s16x8*)(wb + ks * 4096 + c * 512);
            acc[c] = __builtin_amdgcn_mfma_f32_16x16x32_bf16(afr[ks], bfr, acc[c], 0, 0, 0);
        }
    }

    // bias (col = c*16+m)
#pragma unroll
    for (int c = 0; c < 8; ++c) {
        float b = bias[c * 16 + m];
#pragma unroll
        for (int i = 0; i < 4; ++i) acc[c][i] += b;
    }
    // row L2 norm: row = row_base + q*4 + i lives in the 16 lanes of this q-group
    float ss[4];
#pragma unroll
    for (int i = 0; i < 4; ++i) {
        float s = 0.f;
#pragma unroll
        for (int c = 0; c < 8; ++c) s += acc[c][i] * acc[c][i];
        s += __shfl_xor(s, 1); s += __shfl_xor(s, 2);
        s += __shfl_xor(s, 4); s += __shfl_xor(s, 8);
        ss[i] = 1.0f / fmaxf(sqrtf(s), 1e-12f);
    }
#pragma unroll
    for (int c = 0; c < 8; ++c)
#pragma unroll
        for (int i = 0; i < 4; ++i) acc[c][i] *= ss[i];

    if constexpr (MODE == 1) {
        // relu
#pragma unroll
        for (int c = 0; c < 8; ++c)
#pragma unroll
            for (int i = 0; i < 4; ++i) acc[c][i] = fmaxf(acc[c][i], 0.f);
        // store h1 bf16, sliced: feat c*16+m -> slice c>>1, offset (c&1)*16+m
#pragma unroll
        for (int i = 0; i < 4; ++i) {
            int row = row_base + q * 4 + i;
            if (row < N) {
#pragma unroll
                for (int c = 0; c < 8; ++c)
                    outb[(size_t)(c >> 1) * N * 32 + (size_t)row * 32 + (c & 1) * 16 + m] =
                        f2b(acc[c][i]);
            }
        }
        // BN partial sums per col over this wave's 16 rows
        float su[8], sq[8];
#pragma unroll
        for (int c = 0; c < 8; ++c) { su[c] = 0.f; sq[c] = 0.f; }
#pragma unroll
        for (int i = 0; i < 4; ++i) {
            bool vi = (row_base + q * 4 + i) < N;
#pragma unroll
            for (int c = 0; c < 8; ++c) {
                float u = vi ? acc[c][i] : 0.f;
                su[c] += u; sq[c] += u * u;
            }
        }
#pragma unroll
        for (int c = 0; c < 8; ++c) {
            su[c] += __shfl_xor(su[c], 16); su[c] += __shfl_xor(su[c], 32);
            sq[c] += __shfl_xor(sq[c], 16); sq[c] += __shfl_xor(sq[c], 32);
        }
        if (lane < 16) {
#pragma unroll
            for (int c = 0; c < 8; ++c) {
                atomicAdd(&sbuf[c * 16 + m], su[c]);
                atomicAdd(&sbuf[128 + c * 16 + m], sq[c]);
            }
        }
        __syncthreads();
        int shard = (blockIdx.x & 7) * 128;
        if (tid < 128)      atomicAdd(&bnSum[shard + tid], sbuf[tid]);
        else if (tid < 256) atomicAdd(&bnSq[shard + tid - 128], sbuf[tid]);
    } else {
        // fused FC head: out[row][cls] = sum_col h2[row][col]*wfc[cls][col] + bfc
        float o[8][4];
#pragma unroll
        for (int cls = 0; cls < 8; ++cls)
#pragma unroll
            for (int i = 0; i < 4; ++i) o[cls][i] = 0.f;
#pragma unroll
        for (int cls = 0; cls < 8; ++cls) {
#pragma unroll
            for (int c = 0; c < 8; ++c) {
                float wv = sbuf[cls * NF + c * 16 + m];
#pragma unroll
                for (int i = 0; i < 4; ++i) o[cls][i] += acc[c][i] * wv;
            }
#pragma unroll
            for (int i = 0; i < 4; ++i) {
                float t = o[cls][i];
                t += __shfl_xor(t, 1); t += __shfl_xor(t, 2);
                t += __shfl_xor(t, 4); t += __shfl_xor(t, 8);
                o[cls][i] = t;
            }
        }
        float sel[4] = {0.f, 0.f, 0.f, 0.f};
#pragma unroll
        for (int cls = 0; cls < 8; ++cls) {
            bool p = (m == cls);
#pragma unroll
            for (int i = 0; i < 4; ++i) sel[i] = p ? o[cls][i] : sel[i];
        }
        if (m < 8) {
            float bb = bfc[m];
#pragma unroll
            for (int i = 0; i < 4; ++i) {
                int row = row_base + q * 4 + i;
                if (row < N) outf[(size_t)row * 8 + m] = sel[i] + bb;
            }
        }
    }
}

extern "C" void kernel_launch(void* const* d_in, const int* in_sizes, int n_in,
                              void* d_out, int out_size, void* d_ws, size_t ws_size,
                              hipStream_t stream) {
    const float* x   = (const float*)d_in[0];
    const int*   ei  = (const int*)d_in[1];
    const float* W1l = (const float*)d_in[2];
    const float* b1l = (const float*)d_in[3];
    const float* W1r = (const float*)d_in[4];
    const float* gam = (const float*)d_in[5];
    const float* bet = (const float*)d_in[6];
    const float* W2l = (const float*)d_in[7];
    const float* b2l = (const float*)d_in[8];
    const float* W2r = (const float*)d_in[9];
    const float* Wfc = (const float*)d_in[10];
    const float* bfc = (const float*)d_in[11];
    int N = in_sizes[0] / NF;
    int E = in_sizes[1] / 2;

    char* w = (char*)d_ws;
    size_t o = 0;
#define ALO(nbytes) (o = (o + 255) & ~(size_t)255, o += (nbytes), (w + o - (nbytes)))
    int* deg    = (int*)ALO((size_t)N * 4);
    int* cursor = (int*)ALO((size_t)N * 4);
    float* bnSum = (float*)ALO(4096);          // 8 shards x 128
    float* bnSq  = (float*)ALO(4096);
    size_t zwords = o / 4;                     // zero region: deg, cursor, bn shards
    int* offs  = (int*)ALO((size_t)(N + 1) * 4);
    int* bsum  = (int*)ALO(1024);
    int* bbase = (int*)ALO(1024);
    unsigned short* csr = (unsigned short*)ALO((size_t)E * 2);
    unsigned short* wt  = (unsigned short*)ALO((size_t)2 * 65536 * 2);
    float* sbn   = (float*)ALO(512);
    float* bbn   = (float*)ALO(512);
    float* bias2 = (float*)ALO(512);
    unsigned short* xb   = (unsigned short*)ALO((size_t)N * NF * 2);  // sliced [4][N][32]
    unsigned short* aggB = (unsigned short*)ALO((size_t)N * NF * 2);  // sliced
    unsigned short* h1b  = (unsigned short*)ALO((size_t)N * NF * 2);  // sliced
#undef ALO
    (void)ws_size; (void)n_in; (void)out_size;

    int NB = (N + 255) / 256;
    int EB8 = ((E + 255) / 256) * 8;
    int nper = (N + 7) / 8;
    int aggBlocks = ((N + 31) / 32) * 8;
    int LB = (N + 63) / 64;
    int CV = (N * 64 + 255) / 256;
    int ZB = (int)((zwords + 255) / 256);

    k_prep<<<ZB + CV + 24, 256, 0, stream>>>((int*)d_ws, (int)zwords, ZB,
                                             x, (unsigned*)xb, N, W1l, W1r, W2l, wt);
    k_deg<<<EB8, 256, 0, stream>>>(ei, E, deg, nper);
    k_scanA<<<NB, 256, 0, stream>>>(deg, N, bsum);
    k_scanB<<<1, 256, 0, stream>>>(bsum, NB, bbase);
    k_scanC<<<NB, 256, 0, stream>>>(deg, N, bbase, offs);
    k_fill<<<EB8, 256, 0, stream>>>(ei, E, offs, cursor, csr, nper);

    // layer 1
    k_agg<false><<<aggBlocks, 256, 0, stream>>>((const uint4*)xb, csr, offs,
                                                nullptr, nullptr, (uint4*)aggB, N);
    k_lin<1><<<LB, 256, 0, stream>>>(aggB, xb, wt, b1l, nullptr, nullptr,
                                     h1b, nullptr, bnSum, bnSq, N);
    k_prep_w2<<<9, 256, 0, stream>>>(bnSum, bnSq, gam, bet, W2r, b2l,
                                     wt + 65536, bias2, sbn, bbn, (float)N);
    // layer 2 (BN folded: agg epilogue for lin_l, weights for lin_r) + fused FC head
    k_agg<true><<<aggBlocks, 256, 0, stream>>>((const uint4*)h1b, csr, offs,
                                               sbn, bbn, (uint4*)aggB, N);
    k_lin<2><<<LB, 256, 0, stream>>>(aggB, h1b, wt + 65536, bias2, Wfc, bfc,
                                     nullptr, (float*)d_out, nullptr, nullptr, N);
}

// Round 11
// 194.242 us; speedup vs baseline: 1.6648x; 1.0055x over previous
//
#include <hip/hip_runtime.h>
#include <hip/hip_bf16.h>

#define NF 128

typedef float f4 __attribute__((ext_vector_type(4)));
typedef short s16x8 __attribute__((ext_vector_type(8)));
typedef unsigned short u16x8 __attribute__((ext_vector_type(8)));

static __device__ __forceinline__ unsigned short f2b(float f) {
    union { float f; unsigned u; } c; c.f = f;
    unsigned r = c.u + 0x7fffu + ((c.u >> 16) & 1u);
    return (unsigned short)(r >> 16);
}
static __device__ __forceinline__ float blo(unsigned v) { return __uint_as_float(v << 16); }
static __device__ __forceinline__ float bhi(unsigned v) { return __uint_as_float(v & 0xffff0000u); }

// ---------------- fused prep: [0,ZB) zero ws | [ZB,ZB+CV) x->bf16 sliced | +24 w-prep ----
__global__ __launch_bounds__(256) void k_prep(int* __restrict__ zp, int nwords, int ZB,
                                              const float* __restrict__ x,
                                              unsigned* __restrict__ out32, int N,
                                              const float* __restrict__ w0,
                                              const float* __restrict__ w1,
                                              const float* __restrict__ w2,
                                              unsigned short* __restrict__ wt) {
    int b = blockIdx.x;
    if (b < ZB) {
        int i = b * 256 + threadIdx.x;
        if (i < nwords) zp[i] = 0;
    } else if (b < ZB + (N * 64 + 255) / 256) {
        int i = (b - ZB) * 256 + threadIdx.x;
        if (i >= N * 64) return;
        int n = i >> 6, l = i & 63;          // l = feature-pair 0..63
        int s = l >> 4, li = l & 15;         // slice, pair-within-slice
        float2 v = *(const float2*)(x + (size_t)n * NF + l * 2);
        out32[(size_t)s * N * 16 + (size_t)n * 16 + li] =
            (unsigned)f2b(v.x) | ((unsigned)f2b(v.y) << 16);
    } else {
        int t = (b - ZB - (N * 64 + 255) / 256) * 256 + threadIdx.x;   // 0..6143
        if (t >= 6144) return;
        int mat = t >> 11, rem = t & 2047;
        int col = rem >> 4, ks = (rem >> 2) & 3, qq = rem & 3;
        const float* W = (mat == 0) ? w0 : (mat == 1) ? w1 : w2;
        int layer = (mat == 2) ? 1 : 0, half = (mat == 1) ? 1 : 0;
        const float* src = W + col * NF + ks * 32 + qq * 8;
        u16x8 d;
#pragma unroll
        for (int j = 0; j < 8; ++j) d[j] = f2b(src[j]);
        *(u16x8*)(wt + layer * 65536 + (half * 4 + ks) * 4096 + (col >> 4) * 512 +
                  (qq * 16 + (col & 15)) * 8) = d;
    }
}

// ---------------- degree count, XCD-localized ----------------
__global__ __launch_bounds__(256) void k_deg(const int* __restrict__ ei, int E,
                                             int* __restrict__ deg, int nper) {
    int b = blockIdx.x;
    int i = (b >> 3) * 256 + threadIdx.x;
    if (i >= E) return;
    int d = ei[E + i];
    int lo = (b & 7) * nper;
    if (d >= lo && d < lo + nper) atomicAdd(&deg[d], 1);
}

// ---------------- scanA: per-256-chunk sums ----------------
__global__ __launch_bounds__(256) void k_scanA(const int* __restrict__ deg, int N,
                                               int* __restrict__ bsum) {
    __shared__ int red[256];
    int tid = threadIdx.x;
    int i = blockIdx.x * 256 + tid;
    int v = (i < N) ? deg[i] : 0;
    red[tid] = v; __syncthreads();
    for (int s = 128; s > 0; s >>= 1) {
        if (tid < s) red[tid] += red[tid + s];
        __syncthreads();
    }
    if (tid == 0) bsum[blockIdx.x] = red[0];
}

// ---------------- scanC: local scan + inline block-base from bsum (merges old scanB) ----
// Requires gridDim <= 256 chunks (N <= 65536).
__global__ __launch_bounds__(256) void k_scanC(const int* __restrict__ deg, int N,
                                               const int* __restrict__ bsum,
                                               int* __restrict__ offs) {
    __shared__ int sc[256];
    __shared__ int wsum[4];
    int tid = threadIdx.x;
    int i = blockIdx.x * 256 + tid;
    int v = (i < N) ? deg[i] : 0;
    sc[tid] = v; __syncthreads();
    for (int s = 1; s < 256; s <<= 1) {
        int t = (tid >= s) ? sc[tid - s] : 0;
        __syncthreads();
        sc[tid] += t;
        __syncthreads();
    }
    int myinc = sc[tid];
    // base = sum of bsum[0..blockIdx)
    int bv = (tid < blockIdx.x) ? bsum[tid] : 0;
    for (int mm = 1; mm <= 32; mm <<= 1) bv += __shfl_xor(bv, mm);
    if ((tid & 63) == 0) wsum[tid >> 6] = bv;
    __syncthreads();
    int base = wsum[0] + wsum[1] + wsum[2] + wsum[3];
    if (i < N) {
        offs[i] = base + myinc - v;
        if (i == N - 1) offs[N] = base + myinc;   // sentinel = E
    }
}

// ---------------- CSR fill (u16 src), XCD-localized ----------------
__global__ __launch_bounds__(256) void k_fill(const int* __restrict__ ei, int E,
                                              const int* __restrict__ offs,
                                              int* __restrict__ cursor,
                                              unsigned short* __restrict__ csr,
                                              int nper) {
    int b = blockIdx.x;
    int i = (b >> 3) * 256 + threadIdx.x;
    if (i >= E) return;
    int d = ei[E + i];
    int lo = (b & 7) * nper;
    if (d >= lo && d < lo + nper) {
        int p = atomicAdd(&cursor[d], 1);
        csr[offs[d] + p] = (unsigned short)ei[i];
    }
}

// ---------------- BN finalize + layer-2 lin_r weight fold (merged) ----------------
__global__ __launch_bounds__(256) void k_prep_w2(const float* __restrict__ bnSum,
                                                 const float* __restrict__ bnSq,
                                                 const float* __restrict__ gamma,
                                                 const float* __restrict__ beta,
                                                 const float* __restrict__ w2r,
                                                 const float* __restrict__ b2l,
                                                 unsigned short* __restrict__ wtL2,
                                                 float* __restrict__ bias2,
                                                 float* __restrict__ sbn,
                                                 float* __restrict__ bbn, float n) {
    __shared__ float sl[128], bl[128];
    int tid = threadIdx.x;
    if (tid < 128) {
        float su = 0.f, sq = 0.f;
#pragma unroll
        for (int s = 0; s < 8; ++s) { su += bnSum[s * 128 + tid]; sq += bnSq[s * 128 + tid]; }
        float mu = su / n;
        float var = fmaxf(sq / n - mu * mu, 0.f);
        float s = gamma[tid] / sqrtf(var + 1e-5f);
        sl[tid] = s;
        bl[tid] = beta[tid] - mu * s;
    }
    __syncthreads();
    if (blockIdx.x < 8) {
        int t = blockIdx.x * 256 + tid;          // 0..2047
        int col = t >> 4, ks = (t >> 2) & 3, qq = t & 3;
        int k0 = ks * 32 + qq * 8;
        u16x8 d;
#pragma unroll
        for (int j = 0; j < 8; ++j) d[j] = f2b(w2r[col * NF + k0 + j] * sl[k0 + j]);
        *(u16x8*)(wtL2 + (4 + ks) * 4096 + (col >> 4) * 512 +
                  (qq * 16 + (col & 15)) * 8) = d;
    } else {
        if (tid < NF) {
            float s = b2l[tid];
            for (int k = 0; k < NF; ++k) s += w2r[tid * NF + k] * bl[k];
            bias2[tid] = s;
            sbn[tid] = sl[tid];
            bbn[tid] = bl[tid];
        }
    }
}

// ---------------- aggregate, XCD-sliced, uint4 gathers, 4-deep ILP ----------------
template <bool TR>
__global__ __launch_bounds__(256) void k_agg(const uint4* __restrict__ T4all, // [4][N][4]
                                             const unsigned short* __restrict__ csr,
                                             const int* __restrict__ offs,
                                             const float* __restrict__ sbn,
                                             const float* __restrict__ bbn,
                                             uint4* __restrict__ outT4, int N) {
    int b = blockIdx.x;
    int s = (b & 7) >> 1;
    int chunk = (b >> 3) * 2 + (b & 1);
    int tid = threadIdx.x;
    int wid = tid >> 6, lane = tid & 63, g = lane >> 4, li = lane & 15;
    int node = chunk * 16 + wid * 4 + g;
    if (node >= N) return;
    int beg = offs[node], cnt = offs[node + 1] - beg;
    int nb = li >> 2, fq = li & 3;
    const uint4* T4 = T4all + (size_t)s * N * 4;
    const unsigned short* cp = csr + beg;
    float a0 = 0, a1 = 0, a2 = 0, a3 = 0, a4 = 0, a5 = 0, a6 = 0, a7 = 0;
    int j = 0;
    for (; j + 16 <= cnt; j += 16) {
        int sA = cp[j + nb], sB = cp[j + 4 + nb], sC = cp[j + 8 + nb], sD = cp[j + 12 + nb];
        uint4 vA = T4[(size_t)sA * 4 + fq];
        uint4 vB = T4[(size_t)sB * 4 + fq];
        uint4 vC = T4[(size_t)sC * 4 + fq];
        uint4 vD = T4[(size_t)sD * 4 + fq];
        a0 += (blo(vA.x) + blo(vB.x)) + (blo(vC.x) + blo(vD.x));
        a1 += (bhi(vA.x) + bhi(vB.x)) + (bhi(vC.x) + bhi(vD.x));
        a2 += (blo(vA.y) + blo(vB.y)) + (blo(vC.y) + blo(vD.y));
        a3 += (bhi(vA.y) + bhi(vB.y)) + (bhi(vC.y) + bhi(vD.y));
        a4 += (blo(vA.z) + blo(vB.z)) + (blo(vC.z) + blo(vD.z));
        a5 += (bhi(vA.z) + bhi(vB.z)) + (bhi(vC.z) + bhi(vD.z));
        a6 += (blo(vA.w) + blo(vB.w)) + (blo(vC.w) + blo(vD.w));
        a7 += (bhi(vA.w) + bhi(vB.w)) + (bhi(vC.w) + bhi(vD.w));
    }
    for (; j + 8 <= cnt; j += 8) {
        int sA = cp[j + nb], sB = cp[j + 4 + nb];
        uint4 vA = T4[(size_t)sA * 4 + fq];
        uint4 vB = T4[(size_t)sB * 4 + fq];
        a0 += blo(vA.x) + blo(vB.x); a1 += bhi(vA.x) + bhi(vB.x);
        a2 += blo(vA.y) + blo(vB.y); a3 += bhi(vA.y) + bhi(vB.y);
        a4 += blo(vA.z) + blo(vB.z); a5 += bhi(vA.z) + bhi(vB.z);
        a6 += blo(vA.w) + blo(vB.w); a7 += bhi(vA.w) + bhi(vB.w);
    }
    for (; j < cnt; j += 4) {
        int idx = j + nb;
        bool val = idx < cnt;
        int sA = cp[val ? idx : j];
        uint4 vA = T4[(size_t)sA * 4 + fq];
        if (val) {
            a0 += blo(vA.x); a1 += bhi(vA.x);
            a2 += blo(vA.y); a3 += bhi(vA.y);
            a4 += blo(vA.z); a5 += bhi(vA.z);
            a6 += blo(vA.w); a7 += bhi(vA.w);
        }
    }
    a0 += __shfl_xor(a0, 4); a1 += __shfl_xor(a1, 4);
    a2 += __shfl_xor(a2, 4); a3 += __shfl_xor(a3, 4);
    a4 += __shfl_xor(a4, 4); a5 += __shfl_xor(a5, 4);
    a6 += __shfl_xor(a6, 4); a7 += __shfl_xor(a7, 4);
    a0 += __shfl_xor(a0, 8); a1 += __shfl_xor(a1, 8);
    a2 += __shfl_xor(a2, 8); a3 += __shfl_xor(a3, 8);
    a4 += __shfl_xor(a4, 8); a5 += __shfl_xor(a5, 8);
    a6 += __shfl_xor(a6, 8); a7 += __shfl_xor(a7, 8);
    if (li < 4) {
        float id = (cnt > 0) ? 1.0f / (float)cnt : 0.f;
        float r[8] = {a0 * id, a1 * id, a2 * id, a3 * id,
                      a4 * id, a5 * id, a6 * id, a7 * id};
        if (TR) {
            if (cnt > 0) {   // mean(s*v+b) = s*mean(v)+b when deg>0, else 0
                const float2* sc2 = (const float2*)(sbn + s * 32 + fq * 8);
                const float2* bc2 = (const float2*)(bbn + s * 32 + fq * 8);
#pragma unroll
                for (int i = 0; i < 4; ++i) {
                    float2 sc = sc2[i], bc = bc2[i];
                    r[2 * i]     = r[2 * i]     * sc.x + bc.x;
                    r[2 * i + 1] = r[2 * i + 1] * sc.y + bc.y;
                }
            }
        }
        uint4 p;
        p.x = (unsigned)f2b(r[0]) | ((unsigned)f2b(r[1]) << 16);
        p.y = (unsigned)f2b(r[2]) | ((unsigned)f2b(r[3]) << 16);
        p.z = (unsigned)f2b(r[4]) | ((unsigned)f2b(r[5]) << 16);
        p.w = (unsigned)f2b(r[6]) | ((unsigned)f2b(r[7]) << 16);
        outT4[((size_t)s * N + node) * 4 + fq] = p;
    }
}

// ---------------- MFMA linear (+bias +L2norm), LDS weights, 128 rows/block ----------------
// 4 waves; each wave computes TWO 16-row x 128-col tiles sequentially, reusing the
// 64KB LDS weight block (halves per-call weight re-fetch: 50->25 MB). Both tiles'
// A-frags are issued before the staging barrier. Lane-contiguous weight layout ->
// B-frag reads are contiguous 1KB wave-spans (2 lanes/bank, conflict-free).
// C layout: col = lane&15, row = (lane>>4)*4 + reg [m89].
template <int MODE>
__global__ __launch_bounds__(256, 2) void k_lin(
    const unsigned short* __restrict__ aggB,   // sliced [4][N][32] bf16
    const unsigned short* __restrict__ src2,   // sliced [4][N][32] bf16 (xb / h1b)
    const unsigned short* __restrict__ wt,     // layer base, lane-contiguous
    const float* __restrict__ bias,            // [128] (layer2: BN-folded)
    const float* __restrict__ wfc, const float* __restrict__ bfc,   // MODE2
    unsigned short* __restrict__ outb,         // MODE1: h1b sliced [4][N][32]
    float* __restrict__ outf,                  // MODE2: out [N,8]
    float* __restrict__ bnSum, float* __restrict__ bnSq, int N) {
    __shared__ __align__(16) unsigned short wlds[32768];   // 64 KB
    __shared__ float sbuf[1024];                           // 4 KB

    int tid = threadIdx.x;
    int lane = tid & 63;
    int q = lane >> 4, m = lane & 15;
    int wv = tid >> 6;

    // A-frags for both row-tiles, issued before staging (latency hides under it)
    s16x8 afr[2][8];
#pragma unroll
    for (int t = 0; t < 2; ++t) {
        int rb = blockIdx.x * 128 + t * 64 + wv * 16;
        int r = rb + m; if (r >= N) r = N - 1;             // clamp (outputs guarded)
        size_t rr = (size_t)r * 32 + q * 8;
#pragma unroll
        for (int ks = 0; ks < 4; ++ks)
            afr[t][ks] = *(const s16x8*)(aggB + (size_t)ks * N * 32 + rr);
#pragma unroll
        for (int ks = 0; ks < 4; ++ks)
            afr[t][4 + ks] = *(const s16x8*)(src2 + (size_t)ks * N * 32 + rr);
    }
    // stage weights: 4096 f4 = 64 KB, 16 per thread
    {
        const f4* wsrc4 = (const f4*)wt;
        f4* wd4 = (f4*)wlds;
#pragma unroll
        for (int it = 0; it < 16; ++it) wd4[tid + it * 256] = wsrc4[tid + it * 256];
    }
    if constexpr (MODE == 1) {
        if (tid < 256) sbuf[tid] = 0.f;
    } else {
        *(f4*)&sbuf[tid * 4] = ((const f4*)wfc)[tid];      // 1024 floats
    }
    __syncthreads();

    const unsigned short* wb = wlds + lane * 8;            // lane-contiguous

#pragma unroll
    for (int t = 0; t < 2; ++t) {
        int row_base = blockIdx.x * 128 + t * 64 + wv * 16;
        f4 acc[8];
#pragma unroll
        for (int c = 0; c < 8; ++c) acc[c] = (f4){0.f, 0.f, 0.f, 0.f};
#pragma unroll
        for (int ks = 0; ks < 8; ++ks) {
#pragma unroll
            for (int c = 0; c < 8; ++c) {
                s16x8 bfr = *(const s16x8*)(wb + ks * 4096 + c * 512);
                acc[c] = __builtin_amdgcn_mfma_f32_16x16x32_bf16(afr[t][ks], bfr, acc[c], 0, 0, 0);
            }
        }
        // bias (col = c*16+m)
#pragma unroll
        for (int c = 0; c < 8; ++c) {
            float b = bias[c * 16 + m];
#pragma unroll
            for (int i = 0; i < 4; ++i) acc[c][i] += b;
        }
        // row L2 norm (row = row_base + q*4 + i, within 16 lanes of this q-group)
        float ss[4];
#pragma unroll
        for (int i = 0; i < 4; ++i) {
            float s = 0.f;
#pragma unroll
            for (int c = 0; c < 8; ++c) s += acc[c][i] * acc[c][i];
            s += __shfl_xor(s, 1); s += __shfl_xor(s, 2);
            s += __shfl_xor(s, 4); s += __shfl_xor(s, 8);
            ss[i] = 1.0f / fmaxf(sqrtf(s), 1e-12f);
        }
#pragma unroll
        for (int c = 0; c < 8; ++c)
#pragma unroll
            for (int i = 0; i < 4; ++i) acc[c][i] *= ss[i];

        if constexpr (MODE == 1) {
            // relu
#pragma unroll
            for (int c = 0; c < 8; ++c)
#pragma unroll
                for (int i = 0; i < 4; ++i) acc[c][i] = fmaxf(acc[c][i], 0.f);
            // store h1 bf16, sliced: feat c*16+m -> slice c>>1, offset (c&1)*16+m
#pragma unroll
            for (int i = 0; i < 4; ++i) {
                int row = row_base + q * 4 + i;
                if (row < N) {
#pragma unroll
                    for (int c = 0; c < 8; ++c)
                        outb[(size_t)(c >> 1) * N * 32 + (size_t)row * 32 + (c & 1) * 16 + m] =
                            f2b(acc[c][i]);
                }
            }
            // BN partial sums per col over this wave's 16 rows
            float su[8], sq[8];
#pragma unroll
            for (int c = 0; c < 8; ++c) { su[c] = 0.f; sq[c] = 0.f; }
#pragma unroll
            for (int i = 0; i < 4; ++i) {
                bool vi = (row_base + q * 4 + i) < N;
#pragma unroll
                for (int c = 0; c < 8; ++c) {
                    float u = vi ? acc[c][i] : 0.f;
                    su[c] += u; sq[c] += u * u;
                }
            }
#pragma unroll
            for (int c = 0; c < 8; ++c) {
                su[c] += __shfl_xor(su[c], 16); su[c] += __shfl_xor(su[c], 32);
                sq[c] += __shfl_xor(sq[c], 16); sq[c] += __shfl_xor(sq[c], 32);
            }
            if (lane < 16) {
#pragma unroll
                for (int c = 0; c < 8; ++c) {
                    atomicAdd(&sbuf[c * 16 + m], su[c]);
                    atomicAdd(&sbuf[128 + c * 16 + m], sq[c]);
                }
            }
        } else {
            // fused FC head: out[row][cls] = sum_col h2[row][col]*wfc[cls][col] + bfc
            float o[8][4];
#pragma unroll
            for (int cls = 0; cls < 8; ++cls)
#pragma unroll
                for (int i = 0; i < 4; ++i) o[cls][i] = 0.f;
#pragma unroll
            for (int cls = 0; cls < 8; ++cls) {
#pragma unroll
                for (int c = 0; c < 8; ++c) {
                    float wv2 = sbuf[cls * NF + c * 16 + m];
#pragma unroll
                    for (int i = 0; i < 4; ++i) o[cls][i] += acc[c][i] * wv2;
                }
#pragma unroll
                for (int i = 0; i < 4; ++i) {
                    float tt = o[cls][i];
                    tt += __shfl_xor(tt, 1); tt += __shfl_xor(tt, 2);
                    tt += __shfl_xor(tt, 4); tt += __shfl_xor(tt, 8);
                    o[cls][i] = tt;
                }
            }
            float sel[4] = {0.f, 0.f, 0.f, 0.f};
#pragma unroll
            for (int cls = 0; cls < 8; ++cls) {
                bool p = (m == cls);
#pragma unroll
                for (int i = 0; i < 4; ++i) sel[i] = p ? o[cls][i] : sel[i];
            }
            if (m < 8) {
                float bb = bfc[m];
#pragma unroll
                for (int i = 0; i < 4; ++i) {
                    int row = row_base + q * 4 + i;
                    if (row < N) outf[(size_t)row * 8 + m] = sel[i] + bb;
                }
            }
        }
    }

    if constexpr (MODE == 1) {
        __syncthreads();
        int shard = (blockIdx.x & 7) * 128;
        if (tid < 128)      atomicAdd(&bnSum[shard + tid], sbuf[tid]);
        else if (tid < 256) atomicAdd(&bnSq[shard + tid - 128], sbuf[tid]);
    }
}

extern "C" void kernel_launch(void* const* d_in, const int* in_sizes, int n_in,
                              void* d_out, int out_size, void* d_ws, size_t ws_size,
                              hipStream_t stream) {
    const float* x   = (const float*)d_in[0];
    const int*   ei  = (const int*)d_in[1];
    const float* W1l = (const float*)d_in[2];
    const float* b1l = (const float*)d_in[3];
    const float* W1r = (const float*)d_in[4];
    const float* gam = (const float*)d_in[5];
    const float* bet = (const float*)d_in[6];
    const float* W2l = (const float*)d_in[7];
    const float* b2l = (const float*)d_in[8];
    const float* W2r = (const float*)d_in[9];
    const float* Wfc = (const float*)d_in[10];
    const float* bfc = (const float*)d_in[11];
    int N = in_sizes[0] / NF;
    int E = in_sizes[1] / 2;

    char* w = (char*)d_ws;
    size_t o = 0;
#define ALO(nbytes) (o = (o + 255) & ~(size_t)255, o += (nbytes), (w + o - (nbytes)))
    int* deg    = (int*)ALO((size_t)N * 4);
    int* cursor = (int*)ALO((size_t)N * 4);
    float* bnSum = (float*)ALO(4096);          // 8 shards x 128
    float* bnSq  = (float*)ALO(4096);
    size_t zwords = o / 4;                     // zero region: deg, cursor, bn shards
    int* offs  = (int*)ALO((size_t)(N + 1) * 4);
    int* bsum  = (int*)ALO(1024);
    unsigned short* csr = (unsigned short*)ALO((size_t)E * 2);
    unsigned short* wt  = (unsigned short*)ALO((size_t)2 * 65536 * 2);
    float* sbn   = (float*)ALO(512);
    float* bbn   = (float*)ALO(512);
    float* bias2 = (float*)ALO(512);
    unsigned short* xb   = (unsigned short*)ALO((size_t)N * NF * 2);  // sliced [4][N][32]
    unsigned short* aggB = (unsigned short*)ALO((size_t)N * NF * 2);  // sliced
    unsigned short* h1b  = (unsigned short*)ALO((size_t)N * NF * 2);  // sliced
#undef ALO
    (void)ws_size; (void)n_in; (void)out_size;

    int NB = (N + 255) / 256;
    int EB8 = ((E + 255) / 256) * 8;
    int nper = (N + 7) / 8;
    int aggBlocks = ((N + 31) / 32) * 8;
    int LB2 = (N + 127) / 128;
    int CV = (N * 64 + 255) / 256;
    int ZB = (int)((zwords + 255) / 256);

    k_prep<<<ZB + CV + 24, 256, 0, stream>>>((int*)d_ws, (int)zwords, ZB,
                                             x, (unsigned*)xb, N, W1l, W1r, W2l, wt);
    k_deg<<<EB8, 256, 0, stream>>>(ei, E, deg, nper);
    k_scanA<<<NB, 256, 0, stream>>>(deg, N, bsum);
    k_scanC<<<NB, 256, 0, stream>>>(deg, N, bsum, offs);
    k_fill<<<EB8, 256, 0, stream>>>(ei, E, offs, cursor, csr, nper);

    // layer 1
    k_agg<false><<<aggBlocks, 256, 0, stream>>>((const uint4*)xb, csr, offs,
                                                nullptr, nullptr, (uint4*)aggB, N);
    k_lin<1><<<LB2, 256, 0, stream>>>(aggB, xb, wt, b1l, nullptr, nullptr,
                                      h1b, nullptr, bnSum, bnSq, N);
    k_prep_w2<<<9, 256, 0, stream>>>(bnSum, bnSq, gam, bet, W2r, b2l,
                                     wt + 65536, bias2, sbn, bbn, (float)N);
    // layer 2 (BN folded: agg epilogue for lin_l, weights for lin_r) + fused FC head
    k_agg<true><<<aggBlocks, 256, 0, stream>>>((const uint4*)h1b, csr, offs,
                                               sbn, bbn, (uint4*)aggB, N);
    k_lin<2><<<LB2, 256, 0, stream>>>(aggB, h1b, wt + 65536, bias2, Wfc, bfc,
                                      nullptr, (float*)d_out, nullptr, nullptr, N);
}